// Round 1
// baseline (28363.272 us; speedup 1.0000x reference)
//
#include <hip/hip_runtime.h>
#include <hip/hip_fp16.h>

// BiGRU persistent-kernel implementation for MI355X (gfx950).
// B=64, T=512, D=256, U=512. out[b,t,0:U]=fwd h(t); out[b,t,U:2U]=bwd h after t
// steps from the end (reference does NOT re-reverse backward outputs).
//
// Structure: 128 persistent blocks = 2 dirs x 64 unit-slices (8 units each).
// Weights live in VGPRs as fp16 MFMA B-fragments for the whole kernel.
// Per timestep: Phase A (u,r gates, K=768 fused [x_t;h]) -> barrier ->
// Phase B ((r*h)@Whc -> hh -> h_new) -> barrier. Barriers are per-direction
// monotone atomic counters in ws (device scope, correct across XCDs).
// 1 block/CU (launch_bounds(256,1), grid=128 <= 256 CUs) => co-residency
// guaranteed; spin barriers cannot deadlock.

#define BB 64
#define TT 512
#define DD 256
#define UU 512
#define NBD 64        // blocks per direction
#define NJ 8          // units per block (NBD*NJ == UU)
#define LD3U (3*UU)

typedef _Float16 half8 __attribute__((ext_vector_type(8)));
typedef float floatx4 __attribute__((ext_vector_type(4)));

// ---------------- setup: x -> fp16 [T][B][D]; zero h16 + barrier counters ----
__global__ void bigru_setup(const float* __restrict__ x, __half* __restrict__ x16,
                            __half* __restrict__ h16, unsigned* __restrict__ bars) {
    long idx = (long)blockIdx.x * blockDim.x + threadIdx.x;
    if (idx < (long)TT * BB * DD) {
        int t = (int)(idx / (BB * DD));
        int r = (int)(idx % (BB * DD));
        int b = r / DD;
        int d = r % DD;
        x16[idx] = __float2half(x[((long)b * TT + t) * DD + d]);
    }
    if (idx < 2 * 2 * BB * UU) h16[idx] = __float2half(0.0f);  // both parities, both dirs
    if (idx < 64) bars[idx] = 0u;
}

// ---------------- per-direction global barrier (monotone counter) -----------
__device__ __forceinline__ void gbar(unsigned* cnt, unsigned target) {
    __threadfence();            // release: flush this CU's stores device-wide
    __syncthreads();
    if (threadIdx.x == 0) {
        __hip_atomic_fetch_add(cnt, 1u, __ATOMIC_RELAXED, __HIP_MEMORY_SCOPE_AGENT);
        while (__hip_atomic_load(cnt, __ATOMIC_RELAXED, __HIP_MEMORY_SCOPE_AGENT) < target) {
            __builtin_amdgcn_s_sleep(1);
        }
    }
    __syncthreads();
    __threadfence();            // acquire: invalidate stale cached lines
}

// ---------------- persistent BiGRU kernel -----------------------------------
__global__ __launch_bounds__(256, 1) void bigru_persistent(
    const __half* __restrict__ x16,
    const float* __restrict__ Wx_f, const float* __restrict__ Wh_f, const float* __restrict__ b_f,
    const float* __restrict__ Wx_b, const float* __restrict__ Wh_b, const float* __restrict__ b_b,
    __half* __restrict__ h16,    // [parity][dir][B][U] fp16
    __half* __restrict__ rh16,   // [dir][B][U] fp16
    unsigned* __restrict__ bars, // counters at bars[dir*16]
    float* __restrict__ out)     // [B][T][2U] fp32
{
    const int blk  = blockIdx.x;
    const int dir  = blk / NBD;          // 0 = forward, 1 = backward
    const int s    = blk % NBD;
    const int j0   = s * NJ;
    const int tid  = threadIdx.x;
    const int wave = tid >> 6;
    const int lane = tid & 63;
    const int n    = lane & 15;          // MFMA col (C-layout) / A-row (A-layout)
    const int quad = lane >> 4;
    const int mbase = wave * 16;         // this wave's batch-row tile
    const int arow  = mbase + n;         // row this lane loads for A-fragments
    const int koff  = quad * 8;          // k-offset within a K=32 fragment

    const float* Wx = dir ? Wx_b : Wx_f;
    const float* Wh = dir ? Wh_b : Wh_f;
    const float* bv = dir ? b_b  : b_f;

    // ---- one-time: load weight fragments into registers (fp16) ----
    // Phase-A tile packs u-gate (cols 0..7 -> unit j0+n) and r-gate (cols 8..15).
    half8 WA[24];  // [x;h] @ W(:,u|r), K=768
    half8 W3[8];   // x @ Wx(:,c),      K=256 (cols n>=8 zero-padded)
    half8 WC[16];  // rh @ Wh(:,c),     K=512 (cols n>=8 zero-padded)
    const int colur = (n < 8) ? (j0 + n) : (UU + j0 + (n - 8));
#pragma unroll
    for (int f = 0; f < 24; ++f) {
        const int kb = f * 32 + koff;
#pragma unroll
        for (int kk = 0; kk < 8; ++kk) {
            const int k = kb + kk;
            float v = (k < DD) ? Wx[(long)k * LD3U + colur]
                               : Wh[(long)(k - DD) * LD3U + colur];
            WA[f][kk] = (_Float16)v;
        }
    }
#pragma unroll
    for (int f = 0; f < 8; ++f) {
        const int kb = f * 32 + koff;
#pragma unroll
        for (int kk = 0; kk < 8; ++kk) {
            float v = (n < 8) ? Wx[(long)(kb + kk) * LD3U + 2 * UU + j0 + n] : 0.0f;
            W3[f][kk] = (_Float16)v;
        }
    }
#pragma unroll
    for (int f = 0; f < 16; ++f) {
        const int kb = f * 32 + koff;
#pragma unroll
        for (int kk = 0; kk < 8; ++kk) {
            float v = (n < 8) ? Wh[(long)(kb + kk) * LD3U + 2 * UU + j0 + n] : 0.0f;
            WC[f][kk] = (_Float16)v;
        }
    }
    const float bias_ur = (n < 8) ? bv[j0 + n] : bv[UU + j0 + (n - 8)];
    const float bias_c  = (n < 8) ? bv[2 * UU + j0 + n] : 0.0f;

    // h slice owned by this lane (fp32): h[mbase+quad*4+i][j0+n] for n<8
    float h_own[4] = {0.f, 0.f, 0.f, 0.f};
    float u_keep[4] = {0.f, 0.f, 0.f, 0.f};

    unsigned* cnt = bars + dir * 16;
    __half* rhb = rh16 + (long)dir * BB * UU;

    for (int t = 0; t < TT; ++t) {
        const int tx = dir ? (TT - 1 - t) : t;

        // ---------------- Phase A ----------------
        const __half* hin = h16 + (long)((t & 1) * 2 + dir) * BB * UU;
        half8 ax[24];
        const __half* xrow = x16 + ((long)tx * BB + arow) * DD + koff;
#pragma unroll
        for (int f = 0; f < 8; ++f) ax[f] = *(const half8*)(xrow + f * 32);
        const __half* hrow = hin + (long)arow * UU + koff;
#pragma unroll
        for (int f = 0; f < 16; ++f) ax[8 + f] = *(const half8*)(hrow + f * 32);

        floatx4 acc_ur = {0.f, 0.f, 0.f, 0.f};
        floatx4 acc_c  = {0.f, 0.f, 0.f, 0.f};
#pragma unroll
        for (int f = 0; f < 8; ++f) {
            acc_ur = __builtin_amdgcn_mfma_f32_16x16x32_f16(ax[f], WA[f], acc_ur, 0, 0, 0);
            acc_c  = __builtin_amdgcn_mfma_f32_16x16x32_f16(ax[f], W3[f], acc_c, 0, 0, 0);
        }
#pragma unroll
        for (int f = 8; f < 24; ++f)
            acc_ur = __builtin_amdgcn_mfma_f32_16x16x32_f16(ax[f], WA[f], acc_ur, 0, 0, 0);

        // gates: lane(quad,n) holds rows mbase+quad*4+i, col n
#pragma unroll
        for (int i = 0; i < 4; ++i) {
            const float pre = acc_ur[i] + bias_ur;
            const float sg = 1.0f / (1.0f + __expf(-pre));
            // r-lanes (n>=8) need h_own from lane-8 (same quad, col n-8)
            const int src = (n >= 8) ? (lane - 8) : lane;
            const float hov = __shfl(h_own[i], src);
            if (n >= 8) {
                const float rv = sg * hov;
                rhb[(long)(mbase + quad * 4 + i) * UU + j0 + (n - 8)] = __float2half(rv);
            } else {
                u_keep[i] = sg;
            }
        }
        gbar(cnt, (unsigned)NBD * (2u * t + 1u));

        // ---------------- Phase B ----------------
        const __half* rrow = rhb + (long)arow * UU + koff;
        half8 arh[16];
#pragma unroll
        for (int f = 0; f < 16; ++f) arh[f] = *(const half8*)(rrow + f * 32);
#pragma unroll
        for (int f = 0; f < 16; ++f)
            acc_c = __builtin_amdgcn_mfma_f32_16x16x32_f16(arh[f], WC[f], acc_c, 0, 0, 0);

        __half* hout = h16 + (long)(((t + 1) & 1) * 2 + dir) * BB * UU;
        if (n < 8) {
#pragma unroll
            for (int i = 0; i < 4; ++i) {
                float pre = acc_c[i] + bias_c;
                pre = fminf(fmaxf(pre, -15.0f), 15.0f);
                const float e2 = __expf(2.0f * pre);
                const float hh = (e2 - 1.0f) / (e2 + 1.0f);
                const float hn = (1.0f - u_keep[i]) * h_own[i] + u_keep[i] * hh;
                h_own[i] = hn;
                const int row = mbase + quad * 4 + i;
                hout[(long)row * UU + j0 + n] = __float2half(hn);
                out[((long)row * TT + t) * (2 * UU) + (long)dir * UU + j0 + n] = hn;
            }
        }
        gbar(cnt, (unsigned)NBD * (2u * t + 2u));
    }
}

extern "C" void kernel_launch(void* const* d_in, const int* in_sizes, int n_in,
                              void* d_out, int out_size, void* d_ws, size_t ws_size,
                              hipStream_t stream) {
    const float* x    = (const float*)d_in[0];
    const float* Wx_f = (const float*)d_in[1];
    const float* Wh_f = (const float*)d_in[2];
    const float* b_f  = (const float*)d_in[3];
    const float* Wx_b = (const float*)d_in[4];
    const float* Wh_b = (const float*)d_in[5];
    const float* b_b  = (const float*)d_in[6];
    float* out = (float*)d_out;

    char* ws = (char*)d_ws;
    // ws layout (all 256B-aligned): x16 16.78MB | h16 256KB | rh16 128KB | bars
    __half* x16   = (__half*)ws;
    __half* h16   = (__half*)(ws + (size_t)TT * BB * DD * 2);
    __half* rh16  = (__half*)(ws + (size_t)TT * BB * DD * 2 + (size_t)2 * 2 * BB * UU * 2);
    unsigned* bars = (unsigned*)(ws + (size_t)TT * BB * DD * 2 + (size_t)2 * 2 * BB * UU * 2
                                    + (size_t)2 * BB * UU * 2);

    const long nsetup = (long)TT * BB * DD;  // 8.39M threads covers all init ranges
    bigru_setup<<<(int)((nsetup + 255) / 256), 256, 0, stream>>>(x, x16, h16, bars);
    bigru_persistent<<<2 * NBD, 256, 0, stream>>>(x16, Wx_f, Wh_f, b_f, Wx_b, Wh_b, b_b,
                                                  h16, rh16, bars, out);
}

// Round 2
// 6977.105 us; speedup vs baseline: 4.0652x; 4.0652x over previous
//
#include <hip/hip_runtime.h>
#include <hip/hip_fp16.h>

// BiGRU persistent-kernel, round 2: cheap coherence protocol.
// B=64, T=512, D=256, U=512. 128 persistent blocks = 2 dirs x 64 unit-slices.
// Weights in VGPRs as fp16 MFMA B-fragments. Two global sync phases per step.
//
// R1 post-mortem: __threadfence() (agent seq-cst) lowers to buffer_wbl2 (full
// L2 writeback) + buffer_inv per call -> ~27.7us per barrier phase, 28.4ms
// total with everything idle (MfmaUtil 0.29%). R2 protocol:
//   publish:  relaxed agent atomic stores (sc0 sc1 write-through to IC)
//   release:  s_waitcnt vmcnt(0) + __syncthreads + relaxed fetch_add
//   wait:     relaxed spin; one ACQUIRE load on exit (buffer_inv sc1, cheap)
//             -> subsequent plain vector loads re-fetch fresh from IC.
// out[] stores + next-step x prefetch moved into the spin window.

#define BB 64
#define TT 512
#define DD 256
#define UU 512
#define NBD 64        // blocks per direction
#define NJ 8          // units per block (NBD*NJ == UU)
#define LD3U (3*UU)

typedef _Float16 half8 __attribute__((ext_vector_type(8)));
typedef float floatx4 __attribute__((ext_vector_type(4)));

// ---------------- setup: x -> fp16 [T][B][D]; zero h16 + barrier counters ----
__global__ void bigru_setup(const float* __restrict__ x, __half* __restrict__ x16,
                            __half* __restrict__ h16, unsigned* __restrict__ bars) {
    long idx = (long)blockIdx.x * blockDim.x + threadIdx.x;
    if (idx < (long)TT * BB * DD) {
        int t = (int)(idx / (BB * DD));
        int r = (int)(idx % (BB * DD));
        int b = r / DD;
        int d = r % DD;
        x16[idx] = __float2half(x[((long)b * TT + t) * DD + d]);
    }
    if (idx < 2 * 2 * BB * UU) h16[idx] = __float2half(0.0f);  // both parities, both dirs
    if (idx < 64) bars[idx] = 0u;
}

// ---- coherent publish: write-through-to-IC store of one half (2B) ----------
__device__ __forceinline__ void st_agent_half(__half* p, float v) {
    __hip_atomic_store((unsigned short*)p, __half_as_ushort(__float2half(v)),
                       __ATOMIC_RELAXED, __HIP_MEMORY_SCOPE_AGENT);
}

// ---- barrier halves --------------------------------------------------------
__device__ __forceinline__ void bar_arrive(unsigned* cnt) {
    // Drain this wave's sc1 publishes (ack from IC), then one add per block.
    asm volatile("s_waitcnt vmcnt(0)" ::: "memory");
    __syncthreads();
    if (threadIdx.x == 0)
        __hip_atomic_fetch_add(cnt, 1u, __ATOMIC_RELAXED, __HIP_MEMORY_SCOPE_AGENT);
}

__device__ __forceinline__ void bar_wait(unsigned* cnt, unsigned target) {
    if (threadIdx.x == 0) {
        while (__hip_atomic_load(cnt, __ATOMIC_RELAXED, __HIP_MEMORY_SCOPE_AGENT) < target)
            __builtin_amdgcn_s_sleep(1);
        // acquire: emits buffer_inv sc1 so plain loads below see IC-fresh data.
        (void)__hip_atomic_load(cnt, __ATOMIC_ACQUIRE, __HIP_MEMORY_SCOPE_AGENT);
    }
    __syncthreads();
}

// ---------------- persistent BiGRU kernel -----------------------------------
__global__ __launch_bounds__(256, 1) void bigru_persistent(
    const __half* __restrict__ x16,
    const float* __restrict__ Wx_f, const float* __restrict__ Wh_f, const float* __restrict__ b_f,
    const float* __restrict__ Wx_b, const float* __restrict__ Wh_b, const float* __restrict__ b_b,
    __half* __restrict__ h16,    // [parity][dir][B][U] fp16
    __half* __restrict__ rh16,   // [dir][B][U] fp16
    unsigned* __restrict__ bars, // counters at bars[dir*16]
    float* __restrict__ out)     // [B][T][2U] fp32
{
    const int blk  = blockIdx.x;
    const int dir  = blk / NBD;          // 0 = forward, 1 = backward
    const int s    = blk % NBD;
    const int j0   = s * NJ;
    const int tid  = threadIdx.x;
    const int wave = tid >> 6;
    const int lane = tid & 63;
    const int n    = lane & 15;          // MFMA col (C-layout) / A-row (A-layout)
    const int quad = lane >> 4;
    const int mbase = wave * 16;         // this wave's batch-row tile
    const int arow  = mbase + n;         // row this lane loads for A-fragments
    const int koff  = quad * 8;          // k-offset within a K=32 fragment

    const float* Wx = dir ? Wx_b : Wx_f;
    const float* Wh = dir ? Wh_b : Wh_f;
    const float* bv = dir ? b_b  : b_f;

    // ---- one-time: load weight fragments into registers (fp16) ----
    // Phase-A tile packs u-gate (cols 0..7 -> unit j0+n) and r-gate (cols 8..15).
    half8 WA[24];  // [x;h] @ W(:,u|r), K=768
    half8 W3[8];   // x @ Wx(:,c),      K=256 (cols n>=8 zero-padded)
    half8 WC[16];  // rh @ Wh(:,c),     K=512 (cols n>=8 zero-padded)
    const int colur = (n < 8) ? (j0 + n) : (UU + j0 + (n - 8));
#pragma unroll
    for (int f = 0; f < 24; ++f) {
        const int kb = f * 32 + koff;
#pragma unroll
        for (int kk = 0; kk < 8; ++kk) {
            const int k = kb + kk;
            float v = (k < DD) ? Wx[(long)k * LD3U + colur]
                               : Wh[(long)(k - DD) * LD3U + colur];
            WA[f][kk] = (_Float16)v;
        }
    }
#pragma unroll
    for (int f = 0; f < 8; ++f) {
        const int kb = f * 32 + koff;
#pragma unroll
        for (int kk = 0; kk < 8; ++kk) {
            float v = (n < 8) ? Wx[(long)(kb + kk) * LD3U + 2 * UU + j0 + n] : 0.0f;
            W3[f][kk] = (_Float16)v;
        }
    }
#pragma unroll
    for (int f = 0; f < 16; ++f) {
        const int kb = f * 32 + koff;
#pragma unroll
        for (int kk = 0; kk < 8; ++kk) {
            float v = (n < 8) ? Wh[(long)(kb + kk) * LD3U + 2 * UU + j0 + n] : 0.0f;
            WC[f][kk] = (_Float16)v;
        }
    }
    const float bias_ur = (n < 8) ? bv[j0 + n] : bv[UU + j0 + (n - 8)];
    const float bias_c  = (n < 8) ? bv[2 * UU + j0 + n] : 0.0f;

    // h slice owned by this lane (fp32): h[mbase+quad*4+i][j0+n] for n<8
    float h_own[4] = {0.f, 0.f, 0.f, 0.f};
    float u_keep[4] = {0.f, 0.f, 0.f, 0.f};

    unsigned* cnt = bars + dir * 16;
    __half* rhb = rh16 + (long)dir * BB * UU;

    // Prologue: prefetch x fragments for t=0.
    half8 axx[8];
    {
        const int tx0 = dir ? (TT - 1) : 0;
        const __half* xrow = x16 + ((long)tx0 * BB + arow) * DD + koff;
#pragma unroll
        for (int f = 0; f < 8; ++f) axx[f] = *(const half8*)(xrow + f * 32);
    }

    for (int t = 0; t < TT; ++t) {
        // ---------------- Phase A ----------------
        const __half* hin = h16 + (long)((t & 1) * 2 + dir) * BB * UU;
        const __half* hrow = hin + (long)arow * UU + koff;
        half8 ah[16];
#pragma unroll
        for (int f = 0; f < 16; ++f) ah[f] = *(const half8*)(hrow + f * 32);

        floatx4 acc_ur = {0.f, 0.f, 0.f, 0.f};
        floatx4 acc_c  = {0.f, 0.f, 0.f, 0.f};
#pragma unroll
        for (int f = 0; f < 8; ++f) {
            acc_ur = __builtin_amdgcn_mfma_f32_16x16x32_f16(axx[f], WA[f], acc_ur, 0, 0, 0);
            acc_c  = __builtin_amdgcn_mfma_f32_16x16x32_f16(axx[f], W3[f], acc_c, 0, 0, 0);
        }
#pragma unroll
        for (int f = 0; f < 16; ++f)
            acc_ur = __builtin_amdgcn_mfma_f32_16x16x32_f16(ah[f], WA[8 + f], acc_ur, 0, 0, 0);

        // gates: lane(quad,n) holds rows mbase+quad*4+i, col n
#pragma unroll
        for (int i = 0; i < 4; ++i) {
            const float pre = acc_ur[i] + bias_ur;
            const float sg = 1.0f / (1.0f + __expf(-pre));
            // r-lanes (n>=8) need h_own from lane-8 (same quad, col n-8)
            const int src = (n >= 8) ? (lane - 8) : lane;
            const float hov = __shfl(h_own[i], src);
            if (n >= 8) {
                st_agent_half(&rhb[(long)(mbase + quad * 4 + i) * UU + j0 + (n - 8)], sg * hov);
            } else {
                u_keep[i] = sg;
            }
        }
        bar_arrive(cnt);
        bar_wait(cnt, (unsigned)NBD * (2u * (unsigned)t + 1u));

        // ---------------- Phase B ----------------
        const __half* rrow = rhb + (long)arow * UU + koff;
        half8 arh[16];
#pragma unroll
        for (int f = 0; f < 16; ++f) arh[f] = *(const half8*)(rrow + f * 32);
#pragma unroll
        for (int f = 0; f < 16; ++f)
            acc_c = __builtin_amdgcn_mfma_f32_16x16x32_f16(arh[f], WC[f], acc_c, 0, 0, 0);

        __half* hout = h16 + (long)(((t + 1) & 1) * 2 + dir) * BB * UU;
        float hv[4] = {0.f, 0.f, 0.f, 0.f};
        if (n < 8) {
#pragma unroll
            for (int i = 0; i < 4; ++i) {
                float pre = acc_c[i] + bias_c;
                pre = fminf(fmaxf(pre, -15.0f), 15.0f);
                const float e2 = __expf(2.0f * pre);
                const float hh = (e2 - 1.0f) / (e2 + 1.0f);
                const float hn = (1.0f - u_keep[i]) * h_own[i] + u_keep[i] * hh;
                h_own[i] = hn;
                hv[i] = hn;
                const int row = mbase + quad * 4 + i;
                st_agent_half(&hout[(long)row * UU + j0 + n], hn);
            }
        }

        const bool last = (t == TT - 1);
        if (!last) bar_arrive(cnt);

        // ---- overlap window (lane 0 spins; everyone else does useful work) ----
        if (n < 8) {
#pragma unroll
            for (int i = 0; i < 4; ++i) {
                const int row = mbase + quad * 4 + i;
                out[((long)row * TT + t) * (2 * UU) + (long)dir * UU + j0 + n] = hv[i];
            }
        }
        {
            const int tn = last ? t : (t + 1);
            const int txn = dir ? (TT - 1 - tn) : tn;
            const __half* xrow = x16 + ((long)txn * BB + arow) * DD + koff;
#pragma unroll
            for (int f = 0; f < 8; ++f) axx[f] = *(const half8*)(xrow + f * 32);
        }

        if (!last) bar_wait(cnt, (unsigned)NBD * (2u * (unsigned)t + 2u));
    }
}

extern "C" void kernel_launch(void* const* d_in, const int* in_sizes, int n_in,
                              void* d_out, int out_size, void* d_ws, size_t ws_size,
                              hipStream_t stream) {
    const float* x    = (const float*)d_in[0];
    const float* Wx_f = (const float*)d_in[1];
    const float* Wh_f = (const float*)d_in[2];
    const float* b_f  = (const float*)d_in[3];
    const float* Wx_b = (const float*)d_in[4];
    const float* Wh_b = (const float*)d_in[5];
    const float* b_b  = (const float*)d_in[6];
    float* out = (float*)d_out;

    char* ws = (char*)d_ws;
    // ws layout: x16 16.78MB | h16 256KB | rh16 128KB | bars
    __half* x16   = (__half*)ws;
    __half* h16   = (__half*)(ws + (size_t)TT * BB * DD * 2);
    __half* rh16  = (__half*)(ws + (size_t)TT * BB * DD * 2 + (size_t)2 * 2 * BB * UU * 2);
    unsigned* bars = (unsigned*)(ws + (size_t)TT * BB * DD * 2 + (size_t)2 * 2 * BB * UU * 2
                                    + (size_t)2 * BB * UU * 2);

    const long nsetup = (long)TT * BB * DD;  // 8.39M threads covers all init ranges
    bigru_setup<<<(int)((nsetup + 255) / 256), 256, 0, stream>>>(x, x16, h16, bars);
    bigru_persistent<<<2 * NBD, 256, 0, stream>>>(x16, Wx_f, Wh_f, b_f, Wx_b, Wh_b, b_b,
                                                  h16, rh16, bars, out);
}

// Round 3
// 6649.105 us; speedup vs baseline: 4.2657x; 1.0493x over previous
//
#include <hip/hip_runtime.h>
#include <hip/hip_fp16.h>

// BiGRU persistent-kernel, round 3: flag-array barrier (no atomic RMW).
// B=64, T=512, D=256, U=512. 128 persistent blocks = 2 dirs x 64 unit-slices.
// Weights in VGPRs as fp16 MFMA B-fragments. Two global sync phases per step.
//
// R2 post-mortem: single contended fetch_add counter at agent scope serializes
// 64 RMWs per phase (~2.7-5.5us) -> 6.8us/phase. R3: arrival = relaxed agent
// STORE to per-block flag (64 independent words, no serialization); detection
// = wave0's 64 lanes load all 64 flags (one coalesced 256B agent load) +
// __ballot. One ACQUIRE load on exit supplies buffer_inv sc1 (cheap, clean
// inv) so plain vector loads of h/rh see IC-fresh data.
// Also: h-independent x-part MFMAs (16/step) moved into phase-B overlap
// window, so phase A critical path is only the 16 h-dependent MFMAs.

#define BB 64
#define TT 512
#define DD 256
#define UU 512
#define NBD 64        // blocks per direction
#define NJ 8          // units per block (NBD*NJ == UU)
#define LD3U (3*UU)

typedef _Float16 half8 __attribute__((ext_vector_type(8)));
typedef float floatx4 __attribute__((ext_vector_type(4)));

// ---------------- setup: x -> fp16 [T][B][D]; zero h16 + barrier flags ------
__global__ void bigru_setup(const float* __restrict__ x, __half* __restrict__ x16,
                            __half* __restrict__ h16, unsigned* __restrict__ bars) {
    long idx = (long)blockIdx.x * blockDim.x + threadIdx.x;
    if (idx < (long)TT * BB * DD) {
        int t = (int)(idx / (BB * DD));
        int r = (int)(idx % (BB * DD));
        int b = r / DD;
        int d = r % DD;
        x16[idx] = __float2half(x[((long)b * TT + t) * DD + d]);
    }
    if (idx < 2 * 2 * BB * UU) h16[idx] = __float2half(0.0f);  // both parities, both dirs
    if (idx < 1024) bars[idx] = 0u;                            // both dirs' flag arrays
}

// ---- coherent publish: write-through-to-IC store of one half (2B) ----------
__device__ __forceinline__ void st_agent_half(__half* p, float v) {
    __hip_atomic_store((unsigned short*)p, __half_as_ushort(__float2half(v)),
                       __ATOMIC_RELAXED, __HIP_MEMORY_SCOPE_AGENT);
}

// ---- barrier halves (flag array, no RMW) -----------------------------------
__device__ __forceinline__ void bar_arrive(unsigned* flags, int s, unsigned p) {
    // Drain each wave's publishes (ack from IC), then one flag store per block.
    asm volatile("s_waitcnt vmcnt(0)" ::: "memory");
    __syncthreads();
    if (threadIdx.x == 0)
        __hip_atomic_store(&flags[s], p, __ATOMIC_RELAXED, __HIP_MEMORY_SCOPE_AGENT);
}

__device__ __forceinline__ void bar_wait(unsigned* flags, unsigned p) {
    if (threadIdx.x < 64) {
        // Wave 0: lane i polls flags[i]; one coalesced 256B agent load/round.
        for (;;) {
            unsigned v = __hip_atomic_load(&flags[threadIdx.x], __ATOMIC_RELAXED,
                                           __HIP_MEMORY_SCOPE_AGENT);
            if (__ballot(v < p) == 0ull) break;
        }
        if (threadIdx.x == 0)  // acquire: buffer_inv sc1 -> fresh reads below
            (void)__hip_atomic_load(&flags[0], __ATOMIC_ACQUIRE, __HIP_MEMORY_SCOPE_AGENT);
    }
    __syncthreads();
}

// ---------------- persistent BiGRU kernel -----------------------------------
__global__ __launch_bounds__(256, 1) void bigru_persistent(
    const __half* __restrict__ x16,
    const float* __restrict__ Wx_f, const float* __restrict__ Wh_f, const float* __restrict__ b_f,
    const float* __restrict__ Wx_b, const float* __restrict__ Wh_b, const float* __restrict__ b_b,
    __half* __restrict__ h16,    // [parity][dir][B][U] fp16
    __half* __restrict__ rh16,   // [dir][B][U] fp16
    unsigned* __restrict__ bars, // flags: dir0 at [0..64), dir1 at [256..320)
    float* __restrict__ out)     // [B][T][2U] fp32
{
    const int blk  = blockIdx.x;
    const int dir  = blk / NBD;          // 0 = forward, 1 = backward
    const int s    = blk % NBD;
    const int j0   = s * NJ;
    const int tid  = threadIdx.x;
    const int wave = tid >> 6;
    const int lane = tid & 63;
    const int n    = lane & 15;          // MFMA col (C-layout) / A-row (A-layout)
    const int quad = lane >> 4;
    const int mbase = wave * 16;         // this wave's batch-row tile
    const int arow  = mbase + n;         // row this lane loads for A-fragments
    const int koff  = quad * 8;          // k-offset within a K=32 fragment

    const float* Wx = dir ? Wx_b : Wx_f;
    const float* Wh = dir ? Wh_b : Wh_f;
    const float* bv = dir ? b_b  : b_f;

    // ---- one-time: load weight fragments into registers (fp16) ----
    // Phase-A tile packs u-gate (cols 0..7 -> unit j0+n) and r-gate (cols 8..15).
    half8 WA[24];  // [x;h] @ W(:,u|r), K=768
    half8 W3[8];   // x @ Wx(:,c),      K=256 (cols n>=8 zero-padded)
    half8 WC[16];  // rh @ Wh(:,c),     K=512 (cols n>=8 zero-padded)
    const int colur = (n < 8) ? (j0 + n) : (UU + j0 + (n - 8));
#pragma unroll
    for (int f = 0; f < 24; ++f) {
        const int kb = f * 32 + koff;
#pragma unroll
        for (int kk = 0; kk < 8; ++kk) {
            const int k = kb + kk;
            float v = (k < DD) ? Wx[(long)k * LD3U + colur]
                               : Wh[(long)(k - DD) * LD3U + colur];
            WA[f][kk] = (_Float16)v;
        }
    }
#pragma unroll
    for (int f = 0; f < 8; ++f) {
        const int kb = f * 32 + koff;
#pragma unroll
        for (int kk = 0; kk < 8; ++kk) {
            float v = (n < 8) ? Wx[(long)(kb + kk) * LD3U + 2 * UU + j0 + n] : 0.0f;
            W3[f][kk] = (_Float16)v;
        }
    }
#pragma unroll
    for (int f = 0; f < 16; ++f) {
        const int kb = f * 32 + koff;
#pragma unroll
        for (int kk = 0; kk < 8; ++kk) {
            float v = (n < 8) ? Wh[(long)(kb + kk) * LD3U + 2 * UU + j0 + n] : 0.0f;
            WC[f][kk] = (_Float16)v;
        }
    }
    const float bias_ur = (n < 8) ? bv[j0 + n] : bv[UU + j0 + (n - 8)];
    const float bias_c  = (n < 8) ? bv[2 * UU + j0 + n] : 0.0f;

    // h slice owned by this lane (fp32): h[mbase+quad*4+i][j0+n] for n<8
    float h_own[4] = {0.f, 0.f, 0.f, 0.f};
    float u_keep[4] = {0.f, 0.f, 0.f, 0.f};

    unsigned* flags = bars + dir * 256;
    __half* rhb = rh16 + (long)dir * BB * UU;

    // Prologue: x fragments for t=0 + their h-independent MFMAs.
    floatx4 acc_ur = {0.f, 0.f, 0.f, 0.f};
    floatx4 acc_c  = {0.f, 0.f, 0.f, 0.f};
    half8 axx[8];
    {
        const int tx0 = dir ? (TT - 1) : 0;
        const __half* xrow = x16 + ((long)tx0 * BB + arow) * DD + koff;
#pragma unroll
        for (int f = 0; f < 8; ++f) axx[f] = *(const half8*)(xrow + f * 32);
#pragma unroll
        for (int f = 0; f < 8; ++f) {
            acc_ur = __builtin_amdgcn_mfma_f32_16x16x32_f16(axx[f], WA[f], acc_ur, 0, 0, 0);
            acc_c  = __builtin_amdgcn_mfma_f32_16x16x32_f16(axx[f], W3[f], acc_c, 0, 0, 0);
        }
    }

    for (int t = 0; t < TT; ++t) {
        // ---------------- Phase A (critical path: h-part only) ----------------
        const __half* hin = h16 + (long)((t & 1) * 2 + dir) * BB * UU;
        const __half* hrow = hin + (long)arow * UU + koff;
        half8 ah[16];
#pragma unroll
        for (int f = 0; f < 16; ++f) ah[f] = *(const half8*)(hrow + f * 32);
#pragma unroll
        for (int f = 0; f < 16; ++f)
            acc_ur = __builtin_amdgcn_mfma_f32_16x16x32_f16(ah[f], WA[8 + f], acc_ur, 0, 0, 0);

        // gates: lane(quad,n) holds rows mbase+quad*4+i, col n
#pragma unroll
        for (int i = 0; i < 4; ++i) {
            const float pre = acc_ur[i] + bias_ur;
            const float sg = 1.0f / (1.0f + __expf(-pre));
            // r-lanes (n>=8) need h_own from lane-8 (same quad, col n-8)
            const int src = (n >= 8) ? (lane - 8) : lane;
            const float hov = __shfl(h_own[i], src);
            if (n >= 8) {
                st_agent_half(&rhb[(long)(mbase + quad * 4 + i) * UU + j0 + (n - 8)], sg * hov);
            } else {
                u_keep[i] = sg;
            }
        }
        bar_arrive(flags, s, 2u * (unsigned)t + 1u);
        bar_wait(flags, 2u * (unsigned)t + 1u);

        // ---------------- Phase B ----------------
        const __half* rrow = rhb + (long)arow * UU + koff;
        half8 arh[16];
#pragma unroll
        for (int f = 0; f < 16; ++f) arh[f] = *(const half8*)(rrow + f * 32);
#pragma unroll
        for (int f = 0; f < 16; ++f)
            acc_c = __builtin_amdgcn_mfma_f32_16x16x32_f16(arh[f], WC[f], acc_c, 0, 0, 0);

        __half* hout = h16 + (long)(((t + 1) & 1) * 2 + dir) * BB * UU;
        float hv[4] = {0.f, 0.f, 0.f, 0.f};
        if (n < 8) {
#pragma unroll
            for (int i = 0; i < 4; ++i) {
                float pre = acc_c[i] + bias_c;
                pre = fminf(fmaxf(pre, -15.0f), 15.0f);
                const float e2 = __expf(2.0f * pre);
                const float hh = (e2 - 1.0f) / (e2 + 1.0f);
                const float hn = (1.0f - u_keep[i]) * h_own[i] + u_keep[i] * hh;
                h_own[i] = hn;
                hv[i] = hn;
                const int row = mbase + quad * 4 + i;
                st_agent_half(&hout[(long)row * UU + j0 + n], hn);
            }
        }

        const bool last = (t == TT - 1);
        if (!last) bar_arrive(flags, s, 2u * (unsigned)t + 2u);

        // ---- overlap window (hides the wait for other blocks' h publishes) ----
        if (n < 8) {
#pragma unroll
            for (int i = 0; i < 4; ++i) {
                const int row = mbase + quad * 4 + i;
                out[((long)row * TT + t) * (2 * UU) + (long)dir * UU + j0 + n] = hv[i];
            }
        }
        {
            // Prefetch x(t+1) and run its h-independent MFMAs now.
            const int tn = last ? t : (t + 1);
            const int txn = dir ? (TT - 1 - tn) : tn;
            const __half* xrow = x16 + ((long)txn * BB + arow) * DD + koff;
#pragma unroll
            for (int f = 0; f < 8; ++f) axx[f] = *(const half8*)(xrow + f * 32);
            floatx4 nacc_ur = {0.f, 0.f, 0.f, 0.f};
            floatx4 nacc_c  = {0.f, 0.f, 0.f, 0.f};
#pragma unroll
            for (int f = 0; f < 8; ++f) {
                nacc_ur = __builtin_amdgcn_mfma_f32_16x16x32_f16(axx[f], WA[f], nacc_ur, 0, 0, 0);
                nacc_c  = __builtin_amdgcn_mfma_f32_16x16x32_f16(axx[f], W3[f], nacc_c, 0, 0, 0);
            }
            acc_ur = nacc_ur;
            acc_c  = nacc_c;
        }

        if (!last) bar_wait(flags, 2u * (unsigned)t + 2u);
    }
}

extern "C" void kernel_launch(void* const* d_in, const int* in_sizes, int n_in,
                              void* d_out, int out_size, void* d_ws, size_t ws_size,
                              hipStream_t stream) {
    const float* x    = (const float*)d_in[0];
    const float* Wx_f = (const float*)d_in[1];
    const float* Wh_f = (const float*)d_in[2];
    const float* b_f  = (const float*)d_in[3];
    const float* Wx_b = (const float*)d_in[4];
    const float* Wh_b = (const float*)d_in[5];
    const float* b_b  = (const float*)d_in[6];
    float* out = (float*)d_out;

    char* ws = (char*)d_ws;
    // ws layout: x16 16.78MB | h16 256KB | rh16 128KB | bars 4KB
    __half* x16   = (__half*)ws;
    __half* h16   = (__half*)(ws + (size_t)TT * BB * DD * 2);
    __half* rh16  = (__half*)(ws + (size_t)TT * BB * DD * 2 + (size_t)2 * 2 * BB * UU * 2);
    unsigned* bars = (unsigned*)(ws + (size_t)TT * BB * DD * 2 + (size_t)2 * 2 * BB * UU * 2
                                    + (size_t)2 * BB * UU * 2);

    const long nsetup = (long)TT * BB * DD;  // 8.39M threads covers all init ranges
    bigru_setup<<<(int)((nsetup + 255) / 256), 256, 0, stream>>>(x, x16, h16, bars);
    bigru_persistent<<<2 * NBD, 256, 0, stream>>>(x16, Wx_f, Wh_f, b_f, Wx_b, Wh_b, b_b,
                                                  h16, rh16, bars, out);
}